// Round 4
// baseline (684.883 us; speedup 1.0000x reference)
//
#include <hip/hip_runtime.h>
#include <hip/hip_bf16.h>
#include <math.h>

#define NGRAPHS 256
#define PD_EPS 1e-6f
#define POOL_CHUNK 64
#define NCOLOR 16  // csr-build colors; color = blockIdx & 15 -> color c lives on
                   // XCD c%8 (write-merged csr window, R4/R6 lesson). 16 colors
                   // halve the LDS hist/cursor to 25KB -> 6 blocks/CU.
#define CSHIFT 4
#define KB 96      // blocks per color; grid = 1536 = 6/CU = exactly the LDS cap.
// R7: color = blockIdx/KB scatters csr writes across XCDs. Keep blockIdx&15.
// R9: fill/count serial-latency-bound -> 8-deep load pipeline (WIN).
// R10: exact-load agg -> 605us. R11: quad-row gathers cut VMEM instrs 5x ->
// NEUTRAL (42us): agg is latency x per-wave-ILP bound (VALU 26%, HBM 34%,
// nothing saturated; waves just wait on dependent idx->shfl->gather chains).
// R12: pair-of-consecutive-nodes per wave: adjacent csr windows -> one 16-idx
// coalesced load feeds both nodes; 16B/lane gathers (8 rows/instr); uniform
// routing to accA/accB for full blocks, per-element select ONLY on the <=1
// straddle block + tail (tail gathers exec-masked: zero wasted traffic).
// Halves dependent latency steps per wave, doubles independent chains.

typedef __hip_bfloat16 bf16;
typedef unsigned short ushort_t;
typedef short bf8_t __attribute__((ext_vector_type(8)));   // 8 bf16 = 4 VGPRs
typedef float f4_t __attribute__((ext_vector_type(4)));    // MFMA accumulator

static __device__ __forceinline__ int wave_uniform(int v) {
  return __builtin_amdgcn_readfirstlane(v);
}
static __device__ __forceinline__ float b2f(bf16 h) { return __bfloat162float(h); }
static __device__ __forceinline__ bf16 f2b(float f) { return __float2bfloat16(f); }
static __device__ __forceinline__ short f2bbits(float f) {
  bf16 h = __float2bfloat16(f);
  return *reinterpret_cast<short*>(&h);
}
static __device__ __forceinline__ unsigned int pk2(float lo, float hi) {
  return ((unsigned int)(unsigned short)f2bbits(hi) << 16) |
         (unsigned int)(unsigned short)f2bbits(lo);
}
// unpack 8 bf16 (uint4) and accumulate into a[0..7]
static __device__ __forceinline__ void acc8(const uint4 u, float* a) {
  a[0] += __uint_as_float(u.x << 16);
  a[1] += __uint_as_float(u.x & 0xffff0000u);
  a[2] += __uint_as_float(u.y << 16);
  a[3] += __uint_as_float(u.y & 0xffff0000u);
  a[4] += __uint_as_float(u.z << 16);
  a[5] += __uint_as_float(u.z & 0xffff0000u);
  a[6] += __uint_as_float(u.w << 16);
  a[7] += __uint_as_float(u.w & 0xffff0000u);
}
// straddle/tail path: route to A if c else B (u may be zeroed for masked edges)
static __device__ __forceinline__ void acc8sel(const uint4 u, float* A, float* B,
                                               bool c) {
  float v[8];
  v[0] = __uint_as_float(u.x << 16);
  v[1] = __uint_as_float(u.x & 0xffff0000u);
  v[2] = __uint_as_float(u.y << 16);
  v[3] = __uint_as_float(u.y & 0xffff0000u);
  v[4] = __uint_as_float(u.z << 16);
  v[5] = __uint_as_float(u.z & 0xffff0000u);
  v[6] = __uint_as_float(u.w << 16);
  v[7] = __uint_as_float(u.w & 0xffff0000u);
#pragma unroll
  for (int j = 0; j < 8; ++j) {
    A[j] += c ? v[j] : 0.f;
    B[j] += c ? 0.f : v[j];
  }
}

// ---------- pass1: per-(color,block) partial degree histogram in LDS ----------
__global__ __launch_bounds__(256) void k_count_part(const int* __restrict__ dst,
                                                    ushort_t* __restrict__ partial,
                                                    int E, int n, int rng) {
  extern __shared__ int hist[];
  int color = blockIdx.x & (NCOLOR - 1);
  int sub = blockIdx.x >> CSHIFT;
  int base = color * rng;
  int hi = n - base; if (hi > rng) hi = rng;
  for (int i = threadIdx.x; i < rng; i += 256) hist[i] = 0;
  __syncthreads();
  const int stride = KB * 256;
  int e = sub * 256 + threadIdx.x;
  for (; e + 7 * stride < E; e += 8 * stride) {
    int d[8];
#pragma unroll
    for (int k = 0; k < 8; ++k) d[k] = dst[e + k * stride] - base;
#pragma unroll
    for (int k = 0; k < 8; ++k)
      if ((unsigned)d[k] < (unsigned)hi) atomicAdd(&hist[d[k]], 1);
  }
  for (; e < E; e += stride) {
    int d = dst[e] - base;
    if ((unsigned)d < (unsigned)hi) atomicAdd(&hist[d], 1);
  }
  __syncthreads();
  ushort_t* outp = partial + (size_t)blockIdx.x * rng;
  for (int i = threadIdx.x; i < rng; i += 256) outp[i] = (ushort_t)hist[i];
}

// ---------- pass2: reduce partials -> cnt + dinv; partials -> exclusive prefix
__global__ void k_reduce_part(ushort_t* __restrict__ partial, int* __restrict__ cnt,
                              float* __restrict__ dinv, int n, int rng) {
  int i = blockIdx.x * 256 + threadIdx.x;
  if (i >= n) return;
  int c = i / rng, li = i - c * rng;
  int acc = 0;
  for (int s = 0; s < KB; ++s) {
    size_t idx = (size_t)(s * NCOLOR + c) * rng + li;
    int t = partial[idx];
    partial[idx] = (ushort_t)acc;
    acc += t;
  }
  cnt[i] = acc;
  dinv[i] = 1.0f / sqrtf((float)(acc + 1));  // self-loop => deg >= 1
}

// ---------- 3-phase exclusive scan (N=100k) ----------
__global__ void k_scan1(const int* __restrict__ cnt, int* __restrict__ off,
                        int* __restrict__ bsums, int n) {
  __shared__ int s[256];
  int tid = threadIdx.x;
  int gid = blockIdx.x * 256 + tid;
  int v = (gid < n) ? cnt[gid] : 0;
  s[tid] = v; __syncthreads();
  for (int o = 1; o < 256; o <<= 1) {
    int t = (tid >= o) ? s[tid - o] : 0;
    __syncthreads();
    s[tid] += t;
    __syncthreads();
  }
  if (gid < n) off[gid] = s[tid] - v;
  if (tid == 255) bsums[blockIdx.x] = s[255];
}

__global__ void k_scan2(int* __restrict__ bsums, int nb) {
  __shared__ int s[512];
  int tid = threadIdx.x;
  int v = (tid < nb) ? bsums[tid] : 0;
  s[tid] = v; __syncthreads();
  for (int o = 1; o < 512; o <<= 1) {
    int t = (tid >= o) ? s[tid - o] : 0;
    __syncthreads();
    s[tid] += t;
    __syncthreads();
  }
  if (tid < nb) bsums[tid] = s[tid] - v;
}

__global__ void k_off_final(int* __restrict__ off, const int* __restrict__ bsums,
                            int n, int E) {
  int gid = blockIdx.x * 256 + threadIdx.x;
  if (gid < n) off[gid] += bsums[blockIdx.x];
  if (gid == 0) off[n] = E;
}

// ---------- pass4: colored CSR fill (R9: 8-deep unconditional pipeline) ----
__global__ __launch_bounds__(256) void k_fill_col(const int* __restrict__ src,
                                                  const int* __restrict__ dst,
                                                  const int* __restrict__ off,
                                                  const ushort_t* __restrict__ partial,
                                                  int* __restrict__ csr, int E, int n,
                                                  int rng) {
  extern __shared__ int cur[];
  int color = blockIdx.x & (NCOLOR - 1);
  int sub = blockIdx.x >> CSHIFT;
  int base = color * rng;
  int hi = n - base; if (hi > rng) hi = rng;
  const ushort_t* pp = partial + (size_t)blockIdx.x * rng;
  for (int i = threadIdx.x; i < hi; i += 256) cur[i] = off[base + i] + (int)pp[i];
  __syncthreads();
  const int stride = KB * 256;
  int e = sub * 256 + threadIdx.x;
  for (; e + 7 * stride < E; e += 8 * stride) {
    int d[8], s[8];
#pragma unroll
    for (int k = 0; k < 8; ++k) d[k] = dst[e + k * stride] - base;
#pragma unroll
    for (int k = 0; k < 8; ++k) s[k] = src[e + k * stride];  // unconditional: pipeline
#pragma unroll
    for (int k = 0; k < 8; ++k) {
      if ((unsigned)d[k] < (unsigned)hi) {
        int p = atomicAdd(&cur[d[k]], 1);
        csr[p] = s[k];
      }
    }
  }
  for (; e < E; e += stride) {
    int d = dst[e] - base;
    if ((unsigned)d < (unsigned)hi) {
      int p = atomicAdd(&cur[d], 1);
      csr[p] = src[e];
    }
  }
}

// ---------- MFMA GEMM: out[n,f] = dinv[n] * (in[n,:K] @ W[:K,:64]), bf16 out ----
template <int K, int INF32>
__global__ __launch_bounds__(256, 2) void k_gemm_mfma(const void* __restrict__ inv,
                                                      const float* __restrict__ Wg,
                                                      const float* __restrict__ dinv,
                                                      bf16* __restrict__ out, int n) {
  constexpr int KS = K / 32;
  int lane = threadIdx.x & 63;
  int quad = lane >> 4;
  int col = lane & 15;

  bf8_t bfrag[4][KS];
#pragma unroll
  for (int c = 0; c < 4; ++c)
#pragma unroll
    for (int s = 0; s < KS; ++s)
#pragma unroll
      for (int j = 0; j < 8; ++j)
        bfrag[c][s][j] = f2bbits(Wg[(s * 32 + quad * 8 + j) * 64 + c * 16 + col]);

  int wid = (blockIdx.x * blockDim.x + threadIdx.x) >> 6;
  int nw = (gridDim.x * blockDim.x) >> 6;
  int tiles = (n + 15) >> 4;
  for (int t = wid; t < tiles; t += nw) {
    int base = t << 4;
    int arow = base + col;
    if (arow >= n) arow = n - 1;

    bf8_t afrag[KS];
    if (INF32) {
      const float* xr = (const float*)inv + (size_t)arow * K;
#pragma unroll
      for (int s = 0; s < KS; ++s) {
        float4 u0 = *(const float4*)(xr + s * 32 + quad * 8);
        float4 u1 = *(const float4*)(xr + s * 32 + quad * 8 + 4);
        afrag[s][0] = f2bbits(u0.x);
        afrag[s][1] = f2bbits(u0.y);
        afrag[s][2] = f2bbits(u0.z);
        afrag[s][3] = f2bbits(u0.w);
        afrag[s][4] = f2bbits(u1.x);
        afrag[s][5] = f2bbits(u1.y);
        afrag[s][6] = f2bbits(u1.z);
        afrag[s][7] = f2bbits(u1.w);
      }
    } else {
      const bf16* xr = (const bf16*)inv + (size_t)arow * K;
#pragma unroll
      for (int s = 0; s < KS; ++s)
        afrag[s] = *(const bf8_t*)(xr + s * 32 + quad * 8);
    }

    f4_t acc[4];
#pragma unroll
    for (int c = 0; c < 4; ++c) acc[c] = (f4_t){0.f, 0.f, 0.f, 0.f};
#pragma unroll
    for (int s = 0; s < KS; ++s)
#pragma unroll
      for (int c = 0; c < 4; ++c)
        acc[c] = __builtin_amdgcn_mfma_f32_16x16x32_bf16(afrag[s], bfrag[c][s],
                                                         acc[c], 0, 0, 0);
#pragma unroll
    for (int r = 0; r < 4; ++r) {
      int row = base + quad * 4 + r;
      if (row < n) {
        float sc = dinv[row];
#pragma unroll
        for (int c = 0; c < 4; ++c)
          out[(size_t)row * 64 + c * 16 + col] = f2b(acc[c][r] * sc);
      }
    }
  }
}

// ---------- aggregate R12: node-pair per wave, 16B/lane gathers ----------
// lane layout: grp = lane>>3 (8 row-groups), fo = (lane&7)*8 (8 feats, 16B).
// One gather instr = 8 neighbor rows (1KB). Pair (2p, 2p+1): adjacent csr
// windows [off[2p], off[2p+2]) -> one 16-idx coalesced load per block feeds
// both accumulators; block routing is wave-uniform except <=1 straddle block.
template <int OUTF32>
__global__ __launch_bounds__(256) void k_agg(const bf16* __restrict__ hp,
                                             const int* __restrict__ off,
                                             const int* __restrict__ csr,
                                             const float* __restrict__ dinv,
                                             const float* __restrict__ bias,
                                             void* __restrict__ outv, int n,
                                             int do_relu) {
  int lane = threadIdx.x & 63;
  int grp = lane >> 3;
  int fo = (lane & 7) * 8;
  int wid = (blockIdx.x * blockDim.x + threadIdx.x) >> 6;
  int nw = (gridDim.x * blockDim.x) >> 6;
  int npairs = (n + 1) >> 1;

  float4 blo = *(const float4*)(bias + fo);
  float4 bhi = *(const float4*)(bias + fo + 4);
  float bv[8] = {blo.x, blo.y, blo.z, blo.w, bhi.x, bhi.y, bhi.z, bhi.w};

  for (int pr = wid; pr < npairs; pr += nw) {
    int up = wave_uniform(pr);
    int n0 = up * 2;
    int n1 = n0 + 1;
    bool hasB = (n1 < n);
    int beg = off[n0];
    int mid = off[n0 + 1];
    int end = hasB ? off[n0 + 2] : mid;
    int nB = hasB ? n1 : n0;

    // self rows + norms issued early (independent of the gather chain)
    uint4 sA = *(const uint4*)(hp + (size_t)n0 * 64 + fo);
    uint4 sB = *(const uint4*)(hp + (size_t)nB * 64 + fo);
    float dA = dinv[n0];
    float dB = dinv[nB];

    float aA[8] = {0.f, 0.f, 0.f, 0.f, 0.f, 0.f, 0.f, 0.f};
    float aB[8] = {0.f, 0.f, 0.f, 0.f, 0.f, 0.f, 0.f, 0.f};

    int e = beg;
    for (; e + 16 <= end; e += 16) {
      int myidx = (lane < 16) ? csr[e + lane] : 0;
      int i0 = __shfl(myidx, grp);
      int i1 = __shfl(myidx, 8 + grp);
      uint4 u0 = *(const uint4*)(hp + (size_t)i0 * 64 + fo);
      uint4 u1 = *(const uint4*)(hp + (size_t)i1 * 64 + fo);
      if (e >= mid) {            // fully node B (uniform branch)
        acc8(u0, aB); acc8(u1, aB);
      } else if (e + 16 <= mid) { // fully node A (uniform branch)
        acc8(u0, aA); acc8(u1, aA);
      } else {                    // straddle: <=1 block per pair
        acc8sel(u0, aA, aB, (e + grp) < mid);
        acc8sel(u1, aA, aB, (e + 8 + grp) < mid);
      }
    }
    int rem = end - e;  // 0..15, uniform
    if (rem) {
      int myidx = (lane < 16) ? csr[e + ((lane < rem) ? lane : 0)] : 0;
      int i0 = __shfl(myidx, grp);
      int i1 = __shfl(myidx, 8 + grp);
      uint4 u0 = {0u, 0u, 0u, 0u};
      uint4 u1 = {0u, 0u, 0u, 0u};
      if (grp < rem) u0 = *(const uint4*)(hp + (size_t)i0 * 64 + fo);
      if (8 + grp < rem) u1 = *(const uint4*)(hp + (size_t)i1 * 64 + fo);
      acc8sel(u0, aA, aB, (e + grp) < mid);
      acc8sel(u1, aA, aB, (e + 8 + grp) < mid);
    }

    // reduce across the 8 row-groups (xor 8, 16, 32)
#pragma unroll
    for (int j = 0; j < 8; ++j) {
      aA[j] += __shfl_xor(aA[j], 8);
      aB[j] += __shfl_xor(aB[j], 8);
    }
#pragma unroll
    for (int j = 0; j < 8; ++j) {
      aA[j] += __shfl_xor(aA[j], 16);
      aB[j] += __shfl_xor(aB[j], 16);
    }
#pragma unroll
    for (int j = 0; j < 8; ++j) {
      aA[j] += __shfl_xor(aA[j], 32);
      aB[j] += __shfl_xor(aB[j], 32);
    }

    // + self, * dinv, + bias, relu
    float sAv[8], sBv[8];
    uint4 z = sA;
    sAv[0] = __uint_as_float(z.x << 16); sAv[1] = __uint_as_float(z.x & 0xffff0000u);
    sAv[2] = __uint_as_float(z.y << 16); sAv[3] = __uint_as_float(z.y & 0xffff0000u);
    sAv[4] = __uint_as_float(z.z << 16); sAv[5] = __uint_as_float(z.z & 0xffff0000u);
    sAv[6] = __uint_as_float(z.w << 16); sAv[7] = __uint_as_float(z.w & 0xffff0000u);
    z = sB;
    sBv[0] = __uint_as_float(z.x << 16); sBv[1] = __uint_as_float(z.x & 0xffff0000u);
    sBv[2] = __uint_as_float(z.y << 16); sBv[3] = __uint_as_float(z.y & 0xffff0000u);
    sBv[4] = __uint_as_float(z.z << 16); sBv[5] = __uint_as_float(z.z & 0xffff0000u);
    sBv[6] = __uint_as_float(z.w << 16); sBv[7] = __uint_as_float(z.w & 0xffff0000u);

    float rA[8], rB[8];
#pragma unroll
    for (int j = 0; j < 8; ++j) {
      rA[j] = fmaf(aA[j] + sAv[j], dA, bv[j]);
      rB[j] = fmaf(aB[j] + sBv[j], dB, bv[j]);
      if (do_relu) {
        rA[j] = fmaxf(rA[j], 0.f);
        rB[j] = fmaxf(rB[j], 0.f);
      }
    }

    if (grp == 0) {  // lanes 0-7 write node A
      if (OUTF32) {
        float* op = (float*)outv + (size_t)n0 * 64 + fo;
        *(float4*)op = (float4){rA[0], rA[1], rA[2], rA[3]};
        *(float4*)(op + 4) = (float4){rA[4], rA[5], rA[6], rA[7]};
      } else {
        uint4 o = {pk2(rA[0], rA[1]), pk2(rA[2], rA[3]), pk2(rA[4], rA[5]),
                   pk2(rA[6], rA[7])};
        *(uint4*)((bf16*)outv + (size_t)n0 * 64 + fo) = o;
      }
    }
    if (hasB && grp == 1) {  // lanes 8-15 write node B
      if (OUTF32) {
        float* op = (float*)outv + (size_t)n1 * 64 + fo;
        *(float4*)op = (float4){rB[0], rB[1], rB[2], rB[3]};
        *(float4*)(op + 4) = (float4){rB[4], rB[5], rB[6], rB[7]};
      } else {
        uint4 o = {pk2(rB[0], rB[1]), pk2(rB[2], rB[3]), pk2(rB[4], rB[5]),
                   pk2(rB[6], rB[7])};
        *(uint4*)((bf16*)outv + (size_t)n1 * 64 + fo) = o;
      }
    }
  }
}

// ---------- mean-pool: segment-reduce over sorted batch (R2 fix) ----------
__global__ __launch_bounds__(256) void k_pool(const float* __restrict__ x3,
                                              const int* __restrict__ batch,
                                              float* __restrict__ pooled,
                                              float* __restrict__ cnt, int n) {
  int lane = threadIdx.x & 63;
  int wid = (blockIdx.x * blockDim.x + threadIdx.x) >> 6;
  int beg = wid * POOL_CHUNK;
  if (beg >= n) return;
  int end = beg + POOL_CHUNK;
  if (end > n) end = n;

  int cur = wave_uniform(batch[beg]);
  float acc = 0.f;
  int cl = 0;
  int i = beg;
  for (; i + 4 <= end; i += 4) {
    int g0 = wave_uniform(batch[i + 0]);
    int g3 = wave_uniform(batch[i + 3]);
    float a0 = x3[(size_t)(i + 0) * 64 + lane];
    float a1 = x3[(size_t)(i + 1) * 64 + lane];
    float a2 = x3[(size_t)(i + 2) * 64 + lane];
    float a3 = x3[(size_t)(i + 3) * 64 + lane];
    if (g0 == cur && g3 == cur) {
      acc += a0 + a1 + a2 + a3;
      cl += 4;
    } else {
      float av[4] = {a0, a1, a2, a3};
#pragma unroll
      for (int k = 0; k < 4; ++k) {
        int g = wave_uniform(batch[i + k]);
        if (g != cur) {
          atomicAdd(&pooled[cur * 64 + lane], acc);
          if (lane == 0) atomicAdd(&cnt[cur], (float)cl);
          acc = 0.f; cl = 0; cur = g;
        }
        acc += av[k];
        cl += 1;
      }
    }
  }
  for (; i < end; ++i) {
    int g = wave_uniform(batch[i]);
    float a = x3[(size_t)i * 64 + lane];
    if (g != cur) {
      atomicAdd(&pooled[cur * 64 + lane], acc);
      if (lane == 0) atomicAdd(&cnt[cur], (float)cl);
      acc = 0.f; cl = 0; cur = g;
    }
    acc += a;
    cl += 1;
  }
  atomicAdd(&pooled[cur * 64 + lane], acc);
  if (lane == 0) atomicAdd(&cnt[cur], (float)cl);
}

// ---------- head: both 64x64 GEMMs + L2 distance ----------
__global__ void k_final(const float* __restrict__ pooled1, const float* __restrict__ cnt1,
                        const float* __restrict__ pooled2, const float* __restrict__ cnt2,
                        const float* __restrict__ Wlin, const float* __restrict__ blin,
                        float* __restrict__ outp) {
  int g = blockIdx.x;
  int lane = threadIdx.x;  // 64 threads
  float c1 = fmaxf(cnt1[g], 1.f), c2 = fmaxf(cnt2[g], 1.f);
  float p1 = pooled1[g * 64 + lane] / c1;
  float p2 = pooled2[g * 64 + lane] / c2;
  float e1 = blin[lane], e2 = blin[lane];
  for (int j = 0; j < 64; ++j) {
    float w = Wlin[j * 64 + lane];
    e1 = fmaf(__shfl(p1, j), w, e1);
    e2 = fmaf(__shfl(p2, j), w, e2);
  }
  float d = e1 - e2 + PD_EPS;
  float sq = d * d;
  for (int o = 32; o > 0; o >>= 1) sq += __shfl_down(sq, o);
  if (lane == 0) outp[g] = sqrtf(sq);
}

extern "C" void kernel_launch(void* const* d_in, const int* in_sizes, int n_in,
                              void* d_out, int out_size, void* d_ws, size_t ws_size,
                              hipStream_t stream) {
  const float* x1 = (const float*)d_in[0];
  const int* ei1 = (const int*)d_in[1];
  const int* batch1 = (const int*)d_in[2];
  const float* x2 = (const float*)d_in[3];
  const int* ei2 = (const int*)d_in[4];
  const int* batch2 = (const int*)d_in[5];
  const float* W1 = (const float*)d_in[6];
  const float* b1 = (const float*)d_in[7];
  const float* W2 = (const float*)d_in[8];
  const float* b2 = (const float*)d_in[9];
  const float* W3 = (const float*)d_in[10];
  const float* b3 = (const float*)d_in[11];
  const float* Wlin = (const float*)d_in[12];
  const float* blin = (const float*)d_in[13];

  const int N = in_sizes[2];      // 100000
  const int E = in_sizes[1] / 2;  // 1600000
  const int rng = (N + NCOLOR - 1) / NCOLOR;  // nodes per color (6250)

  // workspace carve (~59 MB); partial (1536*6250 ushort = 19.2 MB) aliases
  // bufF (25.6 MB): partial dead after k_fill_col, bufF born at agg3.
  char* p = (char*)d_ws;
  auto alloc = [&](size_t bytes) {
    char* r = p;
    p += (bytes + 255) & ~(size_t)255;
    return r;
  };
  int* off = (int*)alloc((size_t)(N + 1) * 4);
  int* cntn = (int*)alloc((size_t)N * 4);
  int* bsums = (int*)alloc(512 * 4);
  float* dinv = (float*)alloc((size_t)N * 4);
  int* csr = (int*)alloc((size_t)E * 4);
  char* unionbuf = alloc((size_t)N * 64 * 4);  // max(partial 19.2MB, bufF 25.6MB)
  ushort_t* partial = (ushort_t*)unionbuf;
  float* bufF = (float*)unionbuf;
  bf16* hpA = (bf16*)alloc((size_t)N * 64 * 2);
  bf16* hpB = (bf16*)alloc((size_t)N * 64 * 2);
  // pooled1,cnt1,pooled2,cnt2 contiguous -> ONE memset covers all four
  float* pooled1 = (float*)alloc((size_t)NGRAPHS * 64 * 4);
  float* cnt1 = (float*)alloc((size_t)NGRAPHS * 4);
  float* pooled2 = (float*)alloc((size_t)NGRAPHS * 64 * 4);
  float* cnt2 = (float*)alloc((size_t)NGRAPHS * 4);
  size_t poolspan = (size_t)((char*)(cnt2 + NGRAPHS) - (char*)pooled1);

  const int nbN = (N + 255) / 256;
  const size_t ldsB = (size_t)rng * 4;  // 25 KB dynamic LDS -> 6 blocks/CU

  hipMemsetAsync(pooled1, 0, poolspan, stream);

  for (int t = 0; t < 2; ++t) {
    const float* x = t ? x2 : x1;
    const int* src = t ? ei2 : ei1;
    const int* dst = src + E;
    const int* batch = t ? batch2 : batch1;
    float* pooled = t ? pooled2 : pooled1;
    float* cnt = t ? cnt2 : cnt1;

    // CSR build: colored, no device atomics; grid 1536 = 6 blocks/CU
    k_count_part<<<NCOLOR * KB, 256, ldsB, stream>>>(dst, partial, E, N, rng);
    k_reduce_part<<<nbN, 256, 0, stream>>>(partial, cntn, dinv, N, rng);
    k_scan1<<<nbN, 256, 0, stream>>>(cntn, off, bsums, N);
    k_scan2<<<1, 512, 0, stream>>>(bsums, nbN);
    k_off_final<<<nbN, 256, 0, stream>>>(off, bsums, N, E);
    k_fill_col<<<NCOLOR * KB, 256, ldsB, stream>>>(src, dst, off, partial, csr, E, N,
                                                   rng);

    // layer 1 (MFMA, f32 input converted in-register)
    k_gemm_mfma<128, 1><<<512, 256, 0, stream>>>(x, W1, dinv, hpA, N);
    k_agg<0><<<2048, 256, 0, stream>>>(hpA, off, csr, dinv, b1, hpB, N, 1);
    // layer 2
    k_gemm_mfma<64, 0><<<512, 256, 0, stream>>>(hpB, W2, dinv, hpA, N);
    k_agg<0><<<2048, 256, 0, stream>>>(hpA, off, csr, dinv, b2, hpB, N, 1);
    // layer 3 (no relu), agg writes f32 for pooling
    k_gemm_mfma<64, 0><<<512, 256, 0, stream>>>(hpB, W3, dinv, hpA, N);
    k_agg<1><<<2048, 256, 0, stream>>>(hpA, off, csr, dinv, b3, bufF, N, 0);

    const int poolWaves = (N + POOL_CHUNK - 1) / POOL_CHUNK;
    k_pool<<<(poolWaves + 3) / 4, 256, 0, stream>>>(bufF, batch, pooled, cnt, N);
  }
  k_final<<<NGRAPHS, 64, 0, stream>>>(pooled1, cnt1, pooled2, cnt2, Wlin, blin,
                                      (float*)d_out);
}

// Round 5
// 580.617 us; speedup vs baseline: 1.1796x; 1.1796x over previous
//
#include <hip/hip_runtime.h>
#include <hip/hip_bf16.h>
#include <math.h>

#define NGRAPHS 256
#define PD_EPS 1e-6f
#define POOL_CHUNK 64
#define NCOLOR 16  // csr-build colors; color = blockIdx & 15 -> color c lives on
                   // XCD c%8 (write-merged csr window, R4/R6 lesson). 16 colors
                   // halve the LDS hist/cursor to 25KB -> 6 blocks/CU.
#define CSHIFT 4
#define KB 96      // blocks per color; grid = 1536 = 6/CU = exactly the LDS cap.
// R7: color = blockIdx/KB scatters csr writes across XCDs. Keep blockIdx&15.
// R9: fill/count serial-latency-bound -> 8-deep load pipeline (WIN).
// R10: exact-load agg (8-wide + 4/2/1 uniform tail) = the proven-best agg.
// R11 (vector idx + shfl quad-gather): NEUTRAL-to-worse (+3us). R12 (node
// pairs, 16B/lane, select routing): REGRESSED (+10us; VALU 55%, occ 44%).
// Conclusion: R10 agg sits at the fabric wall: 1.6M random 128B rows = 205MB
// of 64B-line L3 traffic / 40us = 5.1 TB/s = fabric ceiling. Don't touch.
// R13: (a) revert agg to exact R10 form; (b) keep merged memset; (c) fold
// layer-3 GEMM out: agg2 emits x' = dinv*relu(r2); agg3 computes
// t_v = dinv_v * (x'_v + sum x'_u) with NO W3/bias; k_final applies
// @W3+b3 then @Wlin+blin (two shfl-dots). Deletes 2 GEMM dispatches + 51MB.

typedef __hip_bfloat16 bf16;
typedef unsigned short ushort_t;
typedef short bf8_t __attribute__((ext_vector_type(8)));   // 8 bf16 = 4 VGPRs
typedef float f4_t __attribute__((ext_vector_type(4)));    // MFMA accumulator

static __device__ __forceinline__ int wave_uniform(int v) {
  return __builtin_amdgcn_readfirstlane(v);
}
static __device__ __forceinline__ float b2f(bf16 h) { return __bfloat162float(h); }
static __device__ __forceinline__ bf16 f2b(float f) { return __float2bfloat16(f); }
static __device__ __forceinline__ short f2bbits(float f) {
  bf16 h = __float2bfloat16(f);
  return *reinterpret_cast<short*>(&h);
}

// ---------- pass1: per-(color,block) partial degree histogram in LDS ----------
__global__ __launch_bounds__(256) void k_count_part(const int* __restrict__ dst,
                                                    ushort_t* __restrict__ partial,
                                                    int E, int n, int rng) {
  extern __shared__ int hist[];
  int color = blockIdx.x & (NCOLOR - 1);
  int sub = blockIdx.x >> CSHIFT;
  int base = color * rng;
  int hi = n - base; if (hi > rng) hi = rng;
  for (int i = threadIdx.x; i < rng; i += 256) hist[i] = 0;
  __syncthreads();
  const int stride = KB * 256;
  int e = sub * 256 + threadIdx.x;
  for (; e + 7 * stride < E; e += 8 * stride) {
    int d[8];
#pragma unroll
    for (int k = 0; k < 8; ++k) d[k] = dst[e + k * stride] - base;
#pragma unroll
    for (int k = 0; k < 8; ++k)
      if ((unsigned)d[k] < (unsigned)hi) atomicAdd(&hist[d[k]], 1);
  }
  for (; e < E; e += stride) {
    int d = dst[e] - base;
    if ((unsigned)d < (unsigned)hi) atomicAdd(&hist[d], 1);
  }
  __syncthreads();
  ushort_t* outp = partial + (size_t)blockIdx.x * rng;
  for (int i = threadIdx.x; i < rng; i += 256) outp[i] = (ushort_t)hist[i];
}

// ---------- pass2: reduce partials -> cnt + dinv; partials -> exclusive prefix
__global__ void k_reduce_part(ushort_t* __restrict__ partial, int* __restrict__ cnt,
                              float* __restrict__ dinv, int n, int rng) {
  int i = blockIdx.x * 256 + threadIdx.x;
  if (i >= n) return;
  int c = i / rng, li = i - c * rng;
  int acc = 0;
  for (int s = 0; s < KB; ++s) {
    size_t idx = (size_t)(s * NCOLOR + c) * rng + li;
    int t = partial[idx];
    partial[idx] = (ushort_t)acc;
    acc += t;
  }
  cnt[i] = acc;
  dinv[i] = 1.0f / sqrtf((float)(acc + 1));  // self-loop => deg >= 1
}

// ---------- 3-phase exclusive scan (N=100k) ----------
__global__ void k_scan1(const int* __restrict__ cnt, int* __restrict__ off,
                        int* __restrict__ bsums, int n) {
  __shared__ int s[256];
  int tid = threadIdx.x;
  int gid = blockIdx.x * 256 + tid;
  int v = (gid < n) ? cnt[gid] : 0;
  s[tid] = v; __syncthreads();
  for (int o = 1; o < 256; o <<= 1) {
    int t = (tid >= o) ? s[tid - o] : 0;
    __syncthreads();
    s[tid] += t;
    __syncthreads();
  }
  if (gid < n) off[gid] = s[tid] - v;
  if (tid == 255) bsums[blockIdx.x] = s[255];
}

__global__ void k_scan2(int* __restrict__ bsums, int nb) {
  __shared__ int s[512];
  int tid = threadIdx.x;
  int v = (tid < nb) ? bsums[tid] : 0;
  s[tid] = v; __syncthreads();
  for (int o = 1; o < 512; o <<= 1) {
    int t = (tid >= o) ? s[tid - o] : 0;
    __syncthreads();
    s[tid] += t;
    __syncthreads();
  }
  if (tid < nb) bsums[tid] = s[tid] - v;
}

__global__ void k_off_final(int* __restrict__ off, const int* __restrict__ bsums,
                            int n, int E) {
  int gid = blockIdx.x * 256 + threadIdx.x;
  if (gid < n) off[gid] += bsums[blockIdx.x];
  if (gid == 0) off[n] = E;
}

// ---------- pass4: colored CSR fill (R9: 8-deep unconditional pipeline) ----
__global__ __launch_bounds__(256) void k_fill_col(const int* __restrict__ src,
                                                  const int* __restrict__ dst,
                                                  const int* __restrict__ off,
                                                  const ushort_t* __restrict__ partial,
                                                  int* __restrict__ csr, int E, int n,
                                                  int rng) {
  extern __shared__ int cur[];
  int color = blockIdx.x & (NCOLOR - 1);
  int sub = blockIdx.x >> CSHIFT;
  int base = color * rng;
  int hi = n - base; if (hi > rng) hi = rng;
  const ushort_t* pp = partial + (size_t)blockIdx.x * rng;
  for (int i = threadIdx.x; i < hi; i += 256) cur[i] = off[base + i] + (int)pp[i];
  __syncthreads();
  const int stride = KB * 256;
  int e = sub * 256 + threadIdx.x;
  for (; e + 7 * stride < E; e += 8 * stride) {
    int d[8], s[8];
#pragma unroll
    for (int k = 0; k < 8; ++k) d[k] = dst[e + k * stride] - base;
#pragma unroll
    for (int k = 0; k < 8; ++k) s[k] = src[e + k * stride];  // unconditional: pipeline
#pragma unroll
    for (int k = 0; k < 8; ++k) {
      if ((unsigned)d[k] < (unsigned)hi) {
        int p = atomicAdd(&cur[d[k]], 1);
        csr[p] = s[k];
      }
    }
  }
  for (; e < E; e += stride) {
    int d = dst[e] - base;
    if ((unsigned)d < (unsigned)hi) {
      int p = atomicAdd(&cur[d], 1);
      csr[p] = src[e];
    }
  }
}

// ---------- MFMA GEMM: out[n,f] = dinv[n] * (in[n,:K] @ W[:K,:64]), bf16 out ----
template <int K, int INF32>
__global__ __launch_bounds__(256, 2) void k_gemm_mfma(const void* __restrict__ inv,
                                                      const float* __restrict__ Wg,
                                                      const float* __restrict__ dinv,
                                                      bf16* __restrict__ out, int n) {
  constexpr int KS = K / 32;
  int lane = threadIdx.x & 63;
  int quad = lane >> 4;
  int col = lane & 15;

  bf8_t bfrag[4][KS];
#pragma unroll
  for (int c = 0; c < 4; ++c)
#pragma unroll
    for (int s = 0; s < KS; ++s)
#pragma unroll
      for (int j = 0; j < 8; ++j)
        bfrag[c][s][j] = f2bbits(Wg[(s * 32 + quad * 8 + j) * 64 + c * 16 + col]);

  int wid = (blockIdx.x * blockDim.x + threadIdx.x) >> 6;
  int nw = (gridDim.x * blockDim.x) >> 6;
  int tiles = (n + 15) >> 4;
  for (int t = wid; t < tiles; t += nw) {
    int base = t << 4;
    int arow = base + col;
    if (arow >= n) arow = n - 1;

    bf8_t afrag[KS];
    if (INF32) {
      const float* xr = (const float*)inv + (size_t)arow * K;
#pragma unroll
      for (int s = 0; s < KS; ++s) {
        float4 u0 = *(const float4*)(xr + s * 32 + quad * 8);
        float4 u1 = *(const float4*)(xr + s * 32 + quad * 8 + 4);
        afrag[s][0] = f2bbits(u0.x);
        afrag[s][1] = f2bbits(u0.y);
        afrag[s][2] = f2bbits(u0.z);
        afrag[s][3] = f2bbits(u0.w);
        afrag[s][4] = f2bbits(u1.x);
        afrag[s][5] = f2bbits(u1.y);
        afrag[s][6] = f2bbits(u1.z);
        afrag[s][7] = f2bbits(u1.w);
      }
    } else {
      const bf16* xr = (const bf16*)inv + (size_t)arow * K;
#pragma unroll
      for (int s = 0; s < KS; ++s)
        afrag[s] = *(const bf8_t*)(xr + s * 32 + quad * 8);
    }

    f4_t acc[4];
#pragma unroll
    for (int c = 0; c < 4; ++c) acc[c] = (f4_t){0.f, 0.f, 0.f, 0.f};
#pragma unroll
    for (int s = 0; s < KS; ++s)
#pragma unroll
      for (int c = 0; c < 4; ++c)
        acc[c] = __builtin_amdgcn_mfma_f32_16x16x32_bf16(afrag[s], bfrag[c][s],
                                                         acc[c], 0, 0, 0);
#pragma unroll
    for (int r = 0; r < 4; ++r) {
      int row = base + quad * 4 + r;
      if (row < n) {
        float sc = dinv[row];
#pragma unroll
        for (int c = 0; c < 4; ++c)
          out[(size_t)row * 64 + c * 16 + col] = f2b(acc[c][r] * sc);
      }
    }
  }
}

// ---------- aggregate (exact R10 form: proven at the fabric wall) ----------
// One node per wave; 8 unconditional gathers in flight per full batch (exactly
// deg loads; wasted loads cost time 1:1). Tail = uniform-branch 4/2/1 rounds.
// MODE 0: out = bf16 relu(dinv*acc + b)                  (layer 1)
// MODE 1: out = bf16 dinv*relu(dinv*acc + b)             (layer 2, emits x')
// MODE 2: out = f32  dinv*acc   (no bias/relu; t_v for folded layer 3)
template <int MODE>
__global__ __launch_bounds__(256) void k_agg(const bf16* __restrict__ hp,
                                             const int* __restrict__ off,
                                             const int* __restrict__ csr,
                                             const float* __restrict__ dinv,
                                             const float* __restrict__ bias,
                                             void* __restrict__ outv, int n) {
  int lane = threadIdx.x & 63;
  int wid = (blockIdx.x * blockDim.x + threadIdx.x) >> 6;
  int nw = (gridDim.x * blockDim.x) >> 6;
  float b = (MODE == 2) ? 0.f : bias[lane];
  for (int node = wid; node < n; node += nw) {
    int un = wave_uniform(node);
    int beg = off[un], end = off[un + 1];
    float acc = b2f(hp[(size_t)un * 64 + lane]);  // self-loop
    int e = beg;
    int efull = beg + ((end - beg) & ~7);
    for (; e < efull; e += 8) {
      int s0 = csr[e + 0], s1 = csr[e + 1], s2 = csr[e + 2], s3 = csr[e + 3];
      int s4 = csr[e + 4], s5 = csr[e + 5], s6 = csr[e + 6], s7 = csr[e + 7];
      float a0 = b2f(hp[(size_t)s0 * 64 + lane]);
      float a1 = b2f(hp[(size_t)s1 * 64 + lane]);
      float a2 = b2f(hp[(size_t)s2 * 64 + lane]);
      float a3 = b2f(hp[(size_t)s3 * 64 + lane]);
      float a4 = b2f(hp[(size_t)s4 * 64 + lane]);
      float a5 = b2f(hp[(size_t)s5 * 64 + lane]);
      float a6 = b2f(hp[(size_t)s6 * 64 + lane]);
      float a7 = b2f(hp[(size_t)s7 * 64 + lane]);
      acc += ((a0 + a1) + (a2 + a3)) + ((a4 + a5) + (a6 + a7));
    }
    int rem = end - e;  // 0..7, wave-uniform -> s_cbranch, no divergence
    if (rem & 4) {
      int s0 = csr[e + 0], s1 = csr[e + 1], s2 = csr[e + 2], s3 = csr[e + 3];
      float a0 = b2f(hp[(size_t)s0 * 64 + lane]);
      float a1 = b2f(hp[(size_t)s1 * 64 + lane]);
      float a2 = b2f(hp[(size_t)s2 * 64 + lane]);
      float a3 = b2f(hp[(size_t)s3 * 64 + lane]);
      acc += (a0 + a1) + (a2 + a3);
      e += 4;
    }
    if (rem & 2) {
      int s0 = csr[e + 0], s1 = csr[e + 1];
      float a0 = b2f(hp[(size_t)s0 * 64 + lane]);
      float a1 = b2f(hp[(size_t)s1 * 64 + lane]);
      acc += a0 + a1;
      e += 2;
    }
    if (rem & 1) {
      acc += b2f(hp[(size_t)csr[e] * 64 + lane]);
    }
    float di = dinv[un];
    if (MODE == 2) {
      ((float*)outv)[(size_t)un * 64 + lane] = acc * di;
    } else {
      float v = fmaf(acc, di, b);
      v = fmaxf(v, 0.f);
      if (MODE == 1) v *= di;  // emit x' = dinv * relu(r)
      ((bf16*)outv)[(size_t)un * 64 + lane] = f2b(v);
    }
  }
}

// ---------- mean-pool: segment-reduce over sorted batch (R2 fix) ----------
__global__ __launch_bounds__(256) void k_pool(const float* __restrict__ x3,
                                              const int* __restrict__ batch,
                                              float* __restrict__ pooled,
                                              float* __restrict__ cnt, int n) {
  int lane = threadIdx.x & 63;
  int wid = (blockIdx.x * blockDim.x + threadIdx.x) >> 6;
  int beg = wid * POOL_CHUNK;
  if (beg >= n) return;
  int end = beg + POOL_CHUNK;
  if (end > n) end = n;

  int cur = wave_uniform(batch[beg]);
  float acc = 0.f;
  int cl = 0;
  int i = beg;
  for (; i + 4 <= end; i += 4) {
    int g0 = wave_uniform(batch[i + 0]);
    int g3 = wave_uniform(batch[i + 3]);
    float a0 = x3[(size_t)(i + 0) * 64 + lane];
    float a1 = x3[(size_t)(i + 1) * 64 + lane];
    float a2 = x3[(size_t)(i + 2) * 64 + lane];
    float a3 = x3[(size_t)(i + 3) * 64 + lane];
    if (g0 == cur && g3 == cur) {
      acc += a0 + a1 + a2 + a3;
      cl += 4;
    } else {
      float av[4] = {a0, a1, a2, a3};
#pragma unroll
      for (int k = 0; k < 4; ++k) {
        int g = wave_uniform(batch[i + k]);
        if (g != cur) {
          atomicAdd(&pooled[cur * 64 + lane], acc);
          if (lane == 0) atomicAdd(&cnt[cur], (float)cl);
          acc = 0.f; cl = 0; cur = g;
        }
        acc += av[k];
        cl += 1;
      }
    }
  }
  for (; i < end; ++i) {
    int g = wave_uniform(batch[i]);
    float a = x3[(size_t)i * 64 + lane];
    if (g != cur) {
      atomicAdd(&pooled[cur * 64 + lane], acc);
      if (lane == 0) atomicAdd(&cnt[cur], (float)cl);
      acc = 0.f; cl = 0; cur = g;
    }
    acc += a;
    cl += 1;
  }
  atomicAdd(&pooled[cur * 64 + lane], acc);
  if (lane == 0) atomicAdd(&cnt[cur], (float)cl);
}

// ---------- head: (mean t)@W3 + b3, then @Wlin + blin, L2 distance ----------
__global__ void k_final(const float* __restrict__ pooled1, const float* __restrict__ cnt1,
                        const float* __restrict__ pooled2, const float* __restrict__ cnt2,
                        const float* __restrict__ W3, const float* __restrict__ b3,
                        const float* __restrict__ Wlin, const float* __restrict__ blin,
                        float* __restrict__ outp) {
  int g = blockIdx.x;
  int lane = threadIdx.x;  // 64 threads
  float c1 = fmaxf(cnt1[g], 1.f), c2 = fmaxf(cnt2[g], 1.f);
  float p1 = pooled1[g * 64 + lane] / c1;
  float p2 = pooled2[g * 64 + lane] / c2;
  // stage 1: q = p @ W3 + b3
  float q1 = b3[lane], q2 = b3[lane];
  for (int j = 0; j < 64; ++j) {
    float w = W3[j * 64 + lane];
    q1 = fmaf(__shfl(p1, j), w, q1);
    q2 = fmaf(__shfl(p2, j), w, q2);
  }
  // stage 2: e = q @ Wlin + blin
  float e1 = blin[lane], e2 = blin[lane];
  for (int j = 0; j < 64; ++j) {
    float w = Wlin[j * 64 + lane];
    e1 = fmaf(__shfl(q1, j), w, e1);
    e2 = fmaf(__shfl(q2, j), w, e2);
  }
  float d = e1 - e2 + PD_EPS;
  float sq = d * d;
  for (int o = 32; o > 0; o >>= 1) sq += __shfl_down(sq, o);
  if (lane == 0) outp[g] = sqrtf(sq);
}

extern "C" void kernel_launch(void* const* d_in, const int* in_sizes, int n_in,
                              void* d_out, int out_size, void* d_ws, size_t ws_size,
                              hipStream_t stream) {
  const float* x1 = (const float*)d_in[0];
  const int* ei1 = (const int*)d_in[1];
  const int* batch1 = (const int*)d_in[2];
  const float* x2 = (const float*)d_in[3];
  const int* ei2 = (const int*)d_in[4];
  const int* batch2 = (const int*)d_in[5];
  const float* W1 = (const float*)d_in[6];
  const float* b1 = (const float*)d_in[7];
  const float* W2 = (const float*)d_in[8];
  const float* b2 = (const float*)d_in[9];
  const float* W3 = (const float*)d_in[10];
  const float* b3 = (const float*)d_in[11];
  const float* Wlin = (const float*)d_in[12];
  const float* blin = (const float*)d_in[13];

  const int N = in_sizes[2];      // 100000
  const int E = in_sizes[1] / 2;  // 1600000
  const int rng = (N + NCOLOR - 1) / NCOLOR;  // nodes per color (6250)

  // workspace carve (~59 MB); partial (1536*6250 ushort = 19.2 MB) aliases
  // bufF (25.6 MB): partial dead after k_fill_col, bufF born at agg3.
  char* p = (char*)d_ws;
  auto alloc = [&](size_t bytes) {
    char* r = p;
    p += (bytes + 255) & ~(size_t)255;
    return r;
  };
  int* off = (int*)alloc((size_t)(N + 1) * 4);
  int* cntn = (int*)alloc((size_t)N * 4);
  int* bsums = (int*)alloc(512 * 4);
  float* dinv = (float*)alloc((size_t)N * 4);
  int* csr = (int*)alloc((size_t)E * 4);
  char* unionbuf = alloc((size_t)N * 64 * 4);  // max(partial 19.2MB, bufF 25.6MB)
  ushort_t* partial = (ushort_t*)unionbuf;
  float* bufF = (float*)unionbuf;
  bf16* hpA = (bf16*)alloc((size_t)N * 64 * 2);
  bf16* hpB = (bf16*)alloc((size_t)N * 64 * 2);
  // pooled1,cnt1,pooled2,cnt2 contiguous -> ONE memset covers all four
  float* pooled1 = (float*)alloc((size_t)NGRAPHS * 64 * 4);
  float* cnt1 = (float*)alloc((size_t)NGRAPHS * 4);
  float* pooled2 = (float*)alloc((size_t)NGRAPHS * 64 * 4);
  float* cnt2 = (float*)alloc((size_t)NGRAPHS * 4);
  size_t poolspan = (size_t)((char*)(cnt2 + NGRAPHS) - (char*)pooled1);

  const int nbN = (N + 255) / 256;
  const size_t ldsB = (size_t)rng * 4;  // 25 KB dynamic LDS -> 6 blocks/CU

  hipMemsetAsync(pooled1, 0, poolspan, stream);

  for (int t = 0; t < 2; ++t) {
    const float* x = t ? x2 : x1;
    const int* src = t ? ei2 : ei1;
    const int* dst = src + E;
    const int* batch = t ? batch2 : batch1;
    float* pooled = t ? pooled2 : pooled1;
    float* cnt = t ? cnt2 : cnt1;

    // CSR build: colored, no device atomics; grid 1536 = 6 blocks/CU
    k_count_part<<<NCOLOR * KB, 256, ldsB, stream>>>(dst, partial, E, N, rng);
    k_reduce_part<<<nbN, 256, 0, stream>>>(partial, cntn, dinv, N, rng);
    k_scan1<<<nbN, 256, 0, stream>>>(cntn, off, bsums, N);
    k_scan2<<<1, 512, 0, stream>>>(bsums, nbN);
    k_off_final<<<nbN, 256, 0, stream>>>(off, bsums, N, E);
    k_fill_col<<<NCOLOR * KB, 256, ldsB, stream>>>(src, dst, off, partial, csr, E, N,
                                                   rng);

    // layer 1 (MFMA, f32 input converted in-register)
    k_gemm_mfma<128, 1><<<512, 256, 0, stream>>>(x, W1, dinv, hpA, N);
    k_agg<0><<<2048, 256, 0, stream>>>(hpA, off, csr, dinv, b1, hpB, N);
    // layer 2 (agg emits x' = dinv * relu(r2))
    k_gemm_mfma<64, 0><<<512, 256, 0, stream>>>(hpB, W2, dinv, hpA, N);
    k_agg<1><<<2048, 256, 0, stream>>>(hpA, off, csr, dinv, b2, hpB, N);
    // layer 3 folded: t_v = dinv_v * (x'_v + sum x'_u); @W3+b3 moved to k_final
    k_agg<2><<<2048, 256, 0, stream>>>(hpB, off, csr, dinv, b3, bufF, N);

    const int poolWaves = (N + POOL_CHUNK - 1) / POOL_CHUNK;
    k_pool<<<(poolWaves + 3) / 4, 256, 0, stream>>>(bufF, batch, pooled, cnt, N);
  }
  k_final<<<NGRAPHS, 64, 0, stream>>>(pooled1, cnt1, pooled2, cnt2, W3, b3, Wlin,
                                      blin, (float*)d_out);
}